// Round 4
// baseline (108.627 us; speedup 1.0000x reference)
//
#include <hip/hip_runtime.h>
#include <math.h>

#define PP 4
#define BB 32
#define NN 2048
#define MM 512
#define DLAT 128
#define BETA_C 1e-3f
#define BIGV 1e9f
#define THREADS 512

// Cross-kernel scratch as a device global: avoids any dependence on ws_size
// (suspected container-killer: OOB writes to an under-sized d_ws).
// Layout: [0..127] qual_sum, [128..255] cov_sum, [256..383] nx, [384..511] ny.
// Every cell is unconditionally rewritten by parts_kernel each launch, so
// graph replays do identical work with no stale state.
__device__ float g_ws[4 * PP * BB];

__device__ __forceinline__ float dist2f4(float4 a, float4 b) {
    float dx = a.x - b.x, dy = a.y - b.y, dz = a.z - b.z;
    return dx * dx + dy * dy + dz * dz;
}

// One block per (batch b, part i, phase). phase 0: quality (min over y per x),
// phase 1: coverage (min over x per y).
__global__ __launch_bounds__(THREADS) void parts_kernel(
    const float* __restrict__ ipt,    // (B,N,3)
    const float* __restrict__ opt,    // (P,B,M,3)
    const float* __restrict__ trans,  // (P,B,3)
    const float* __restrict__ rots,   // (P,B,4)
    const int*   __restrict__ idx)    // (B,N)
{
    const int b = blockIdx.x;
    const int i = blockIdx.y;
    const int phase = blockIdx.z;
    const int tid = threadIdx.x;

    __shared__ float Rm[9], tv[3];
    __shared__ int s_nx, s_ny;
    __shared__ float4 sy[MM];   // y points; invalid rows -> 1e8 coords, .w = valid flag
    __shared__ float4 sx[NN];   // compacted transformed x points for this part
    __shared__ float red[THREADS / 64];

    if (tid == 0) {
        s_nx = 0;
        s_ny = 0;
        const float* q = rots + (i * BB + b) * 4;
        float qw = q[0], qx = q[1], qy = q[2], qz = q[3];
        float inv = 1.0f / sqrtf(qw * qw + qx * qx + qy * qy + qz * qz);
        qw *= inv; qx *= inv; qy *= inv; qz *= inv;
        Rm[0] = 1.0f - 2.0f * (qy * qy + qz * qz);
        Rm[1] = 2.0f * (qx * qy - qw * qz);
        Rm[2] = 2.0f * (qx * qz + qw * qy);
        Rm[3] = 2.0f * (qx * qy + qw * qz);
        Rm[4] = 1.0f - 2.0f * (qx * qx + qz * qz);
        Rm[5] = 2.0f * (qy * qz - qw * qx);
        Rm[6] = 2.0f * (qx * qz - qw * qy);
        Rm[7] = 2.0f * (qy * qz + qw * qx);
        Rm[8] = 1.0f - 2.0f * (qx * qx + qy * qy);
        const float* t = trans + (i * BB + b) * 3;
        tv[0] = t[0]; tv[1] = t[1]; tv[2] = t[2];
    }
    __syncthreads();

    // stage y into LDS
    int cnt = 0;
    for (int m = tid; m < MM; m += THREADS) {
        const float* y = opt + (((size_t)i * BB + b) * MM + m) * 3;
        float yx = y[0], yy = y[1], yz = y[2];
        bool v = (yx != 0.0f) | (yy != 0.0f) | (yz != 0.0f);
        if (v) cnt++;
        else { yx = 1e8f; yy = 1e8f; yz = 1e8f; }  // sentinel: farther than any real point
        sy[m] = make_float4(yx, yy, yz, v ? 1.0f : 0.0f);
    }
    if (cnt) atomicAdd(&s_ny, cnt);

    // compact transformed x points belonging to part i
    const float R0 = Rm[0], R1 = Rm[1], R2 = Rm[2];
    const float R3 = Rm[3], R4 = Rm[4], R5 = Rm[5];
    const float R6 = Rm[6], R7 = Rm[7], R8 = Rm[8];
    const float t0 = tv[0], t1 = tv[1], t2 = tv[2];
    for (int n = tid; n < NN; n += THREADS) {
        const float* p = ipt + ((size_t)b * NN + n) * 3;
        float px = p[0], py = p[1], pz = p[2];
        bool nz = (px != 0.0f) | (py != 0.0f) | (pz != 0.0f);
        if (nz && idx[b * NN + n] == i) {
            px -= t0; py -= t1; pz -= t2;
            float lx = R0 * px + R1 * py + R2 * pz;
            float ly = R3 * px + R4 * py + R5 * pz;
            float lz = R6 * px + R7 * py + R8 * pz;
            int pos = atomicAdd(&s_nx, 1);
            sx[pos] = make_float4(lx, ly, lz, 0.0f);
        }
    }
    __syncthreads();
    const int nx = s_nx;
    const int ny = s_ny;

    float sum = 0.0f;
    if (phase == 0) {
        // quality: for each selected x, min over y
        for (int k = tid; k < nx; k += THREADS) {
            float4 p = sx[k];
            float m0 = BIGV, m1 = BIGV, m2 = BIGV, m3 = BIGV;
            for (int m = 0; m < MM; m += 4) {   // wave-uniform LDS reads -> broadcast
                m0 = fminf(m0, dist2f4(p, sy[m]));
                m1 = fminf(m1, dist2f4(p, sy[m + 1]));
                m2 = fminf(m2, dist2f4(p, sy[m + 2]));
                m3 = fminf(m3, dist2f4(p, sy[m + 3]));
            }
            sum += fminf(fminf(m0, m1), fminf(m2, m3));
        }
    } else {
        // coverage: for each valid y, min over selected x
        for (int m = tid; m < MM; m += THREADS) {
            float4 q = sy[m];
            if (q.w != 0.0f) {
                float m0 = BIGV, m1 = BIGV, m2 = BIGV, m3 = BIGV;
                int k = 0;
                for (; k + 4 <= nx; k += 4) {
                    m0 = fminf(m0, dist2f4(q, sx[k]));
                    m1 = fminf(m1, dist2f4(q, sx[k + 1]));
                    m2 = fminf(m2, dist2f4(q, sx[k + 2]));
                    m3 = fminf(m3, dist2f4(q, sx[k + 3]));
                }
                float dmin = fminf(fminf(m0, m1), fminf(m2, m3));
                for (; k < nx; ++k) dmin = fminf(dmin, dist2f4(q, sx[k]));
                sum += dmin;   // nx==0 -> BIGV, matches reference's masked-BIG path
            }
        }
    }

    // block reduction (wave64 shuffle + LDS)
    for (int off = 32; off > 0; off >>= 1) sum += __shfl_down(sum, off);
    if ((tid & 63) == 0) red[tid >> 6] = sum;
    __syncthreads();
    if (tid == 0) {
        float tot = 0.0f;
        for (int w = 0; w < THREADS / 64; ++w) tot += red[w];
        int pb = i * BB + b;
        if (phase == 0) {
            g_ws[pb] = tot;
            g_ws[2 * PP * BB + pb] = (float)nx;
        } else {
            g_ws[PP * BB + pb] = tot;
            g_ws[3 * PP * BB + pb] = (float)ny;
        }
    }
}

__global__ __launch_bounds__(256) void finalize_kernel(
    const float* __restrict__ probs,   // (P,B,1)
    const float* __restrict__ mu,      // (B,DLAT)
    const float* __restrict__ logvar,  // (B,DLAT)
    float* __restrict__ out)
{
    const int tid = threadIdx.x;
    __shared__ float red[4];
    __shared__ float s_wq[PP * BB], s_wc[PP * BB], s_val[PP * BB];

    // KL: sum over B*DLAT of (1 + lv - mu^2 - exp(lv))
    float kls = 0.0f;
    for (int t = tid; t < BB * DLAT; t += 256) {
        float m_ = mu[t], lv = logvar[t];
        kls += 1.0f + lv - m_ * m_ - expf(lv);
    }
    for (int off = 32; off > 0; off >>= 1) kls += __shfl_down(kls, off);
    if ((tid & 63) == 0) red[tid >> 6] = kls;

    if (tid < PP * BB) {
        float qs = g_ws[tid];
        float cs = g_ws[PP * BB + tid];
        float nxf = g_ws[2 * PP * BB + tid];
        float nyf = g_ws[3 * PP * BB + tid];
        bool valid = (nxf > 0.0f) && (nyf > 0.0f);
        float w = valid ? probs[tid] : 0.0f;
        s_wq[tid] = w * (qs / fmaxf(nxf, 1.0f));
        s_wc[tid] = w * (cs / fmaxf(nyf, 1.0f));
        s_val[tid] = valid ? 1.0f : 0.0f;
    }
    __syncthreads();

    if (tid == 0) {
        float kld = -0.5f * (red[0] + red[1] + red[2] + red[3]) / (float)BB;
        float ch = 0.0f, cov = 0.0f, qu = 0.0f, num = 0.0f;
        for (int i = 0; i < PP; ++i) {
            float sq = 0.0f, sc = 0.0f, n = 0.0f;
            for (int bb = 0; bb < BB; ++bb) {
                sq += s_wq[i * BB + bb];
                sc += s_wc[i * BB + bb];
                n += s_val[i * BB + bb];
            }
            float has = (n > 0.0f) ? 1.0f : 0.0f;
            float invn = has / fmaxf(n, 1.0f);
            qu += sq * invn;
            cov += sc * invn;
            ch += (sq + sc) * invn;
            num += has;
        }
        float invnum = 1.0f / fmaxf(num, 1.0f);
        float cds = ch * invnum;
        out[0] = cds + BETA_C * kld;
        out[1] = cds;
        out[2] = cov * invnum;
        out[3] = qu * invnum;
        out[4] = kld;
    }
}

extern "C" void kernel_launch(void* const* d_in, const int* in_sizes, int n_in,
                              void* d_out, int out_size, void* d_ws, size_t ws_size,
                              hipStream_t stream) {
    const float* ipt    = (const float*)d_in[0];
    const float* opt    = (const float*)d_in[1];
    const float* trans  = (const float*)d_in[2];
    const float* rots   = (const float*)d_in[3];
    const float* probs  = (const float*)d_in[4];
    const int*   idx    = (const int*)d_in[5];
    const float* mu     = (const float*)d_in[6];
    const float* logvar = (const float*)d_in[7];
    float* out = (float*)d_out;
    (void)d_ws; (void)ws_size; (void)in_sizes; (void)n_in; (void)out_size;

    dim3 grid(BB, PP, 2);
    parts_kernel<<<grid, THREADS, 0, stream>>>(ipt, opt, trans, rots, idx);
    finalize_kernel<<<1, 256, 0, stream>>>(probs, mu, logvar, out);
}